// Round 1
// baseline (8360.730 us; speedup 1.0000x reference)
//
#include <hip/hip_runtime.h>
#include <math.h>

#define D 768

// ============================ copy ============================
__global__ __launch_bounds__(256) void copy_f4(const float4* __restrict__ in,
                                               float4* __restrict__ out, int n) {
  int i = blockIdx.x * blockDim.x + threadIdx.x;
  if (i < n) out[i] = in[i];
}

// ============================ row norms ============================
__global__ __launch_bounds__(64) void norms_k(const float* __restrict__ tok,
                                              float* __restrict__ norms, int N) {
  int row = blockIdx.x;
  if (row >= N) return;
  const float* r = tok + (size_t)row * D;
  float s = 0.f;
  for (int k = threadIdx.x; k < D; k += 64) { float v = r[k]; s += v * v; }
#pragma unroll
  for (int off = 32; off > 0; off >>= 1) s += __shfl_down(s, off);
  if (threadIdx.x == 0) norms[row] = sqrtf(s);
}

// ============== cosine-sim tile (32 rows x 64 cols) + per-row top-2 partial ==============
// Ties broken toward lower column index (matches jax.lax.top_k) via strict-> insertion
// scanned in ascending column order. part[row*nChunks + chunk] = {v1, i1, v2, i2}.
__global__ __launch_bounds__(256) void sim_top2_part(
    const float* __restrict__ tok, const float* __restrict__ norms,
    int nRows, int nCols, int nChunks, float4* __restrict__ part) {
  __shared__ float As[32][65];
  __shared__ float Bs[64][65];
  __shared__ float Ss[32][65];
  int tid = threadIdx.x;
  int rowBase = blockIdx.y * 32, colBase = blockIdx.x * 64;
  int r0 = (tid >> 5) << 2;   // (tid/32)*4 : 0..28
  int c0 = (tid & 31) << 1;   // (tid%32)*2 : 0..62
  float acc00=0.f,acc01=0.f,acc10=0.f,acc11=0.f,acc20=0.f,acc21=0.f,acc30=0.f,acc31=0.f;
  for (int kb = 0; kb < D; kb += 64) {
    for (int i = tid; i < 32 * 64; i += 256) {
      int r = i >> 6, kk = i & 63;
      int row = rowBase + r;
      As[r][kk] = (row < nRows) ? tok[(size_t)row * D + kb + kk] : 0.f;
    }
    for (int i = tid; i < 64 * 64; i += 256) {
      int r = i >> 6, kk = i & 63;
      int col = colBase + r;
      Bs[r][kk] = (col < nCols) ? tok[(size_t)col * D + kb + kk] : 0.f;
    }
    __syncthreads();
#pragma unroll
    for (int kk = 0; kk < 64; kk++) {
      float a0 = As[r0 + 0][kk], a1 = As[r0 + 1][kk], a2 = As[r0 + 2][kk], a3 = As[r0 + 3][kk];
      float b0 = Bs[c0 + 0][kk], b1 = Bs[c0 + 1][kk];
      acc00 += a0 * b0; acc01 += a0 * b1;
      acc10 += a1 * b0; acc11 += a1 * b1;
      acc20 += a2 * b0; acc21 += a2 * b1;
      acc30 += a3 * b0; acc31 += a3 * b1;
    }
    __syncthreads();
  }
  int row0 = rowBase + r0;
  float na0 = (row0 + 0 < nRows) ? norms[row0 + 0] : 1.f;
  float na1 = (row0 + 1 < nRows) ? norms[row0 + 1] : 1.f;
  float na2 = (row0 + 2 < nRows) ? norms[row0 + 2] : 1.f;
  float na3 = (row0 + 3 < nRows) ? norms[row0 + 3] : 1.f;
  int col0 = colBase + c0, col1 = col0 + 1;
  float nc0 = (col0 < nCols) ? norms[col0] : 1.f;
  float nc1 = (col1 < nCols) ? norms[col1] : 1.f;
  bool ok0 = (col0 < nCols), ok1 = (col1 < nCols);
  Ss[r0 + 0][c0 + 0] = ok0 ? acc00 / fmaxf(na0 * nc0, 1e-8f) : -INFINITY;
  Ss[r0 + 0][c0 + 1] = ok1 ? acc01 / fmaxf(na0 * nc1, 1e-8f) : -INFINITY;
  Ss[r0 + 1][c0 + 0] = ok0 ? acc10 / fmaxf(na1 * nc0, 1e-8f) : -INFINITY;
  Ss[r0 + 1][c0 + 1] = ok1 ? acc11 / fmaxf(na1 * nc1, 1e-8f) : -INFINITY;
  Ss[r0 + 2][c0 + 0] = ok0 ? acc20 / fmaxf(na2 * nc0, 1e-8f) : -INFINITY;
  Ss[r0 + 2][c0 + 1] = ok1 ? acc21 / fmaxf(na2 * nc1, 1e-8f) : -INFINITY;
  Ss[r0 + 3][c0 + 0] = ok0 ? acc30 / fmaxf(na3 * nc0, 1e-8f) : -INFINITY;
  Ss[r0 + 3][c0 + 1] = ok1 ? acc31 / fmaxf(na3 * nc1, 1e-8f) : -INFINITY;
  __syncthreads();
  if (tid < 32) {
    int row = rowBase + tid;
    if (row < nRows) {
      float v1 = -INFINITY, v2 = -INFINITY;
      int i1 = -1, i2 = -1;
      for (int c = 0; c < 64; c++) {
        float v = Ss[tid][c];
        int id = colBase + c;
        if (v > v1) { v2 = v1; i2 = i1; v1 = v; i1 = id; }
        else if (v > v2) { v2 = v; i2 = id; }
      }
      part[(size_t)row * nChunks + blockIdx.x] =
          make_float4(v1, __int_as_float(i1), v2, __int_as_float(i2));
    }
  }
}

// ============== reduce chunk partials -> final (a,b) pair per row ==============
__global__ __launch_bounds__(256) void top2_reduce(const float4* __restrict__ part,
                                                   int nRows, int nChunks,
                                                   int2* __restrict__ pairs) {
  int row = blockIdx.x * 256 + threadIdx.x;
  if (row >= nRows) return;
  float v1 = -INFINITY, v2 = -INFINITY;
  int i1 = -1, i2 = -1;
  for (int c = 0; c < nChunks; c++) {  // ascending chunk order = ascending index order
    float4 p = part[(size_t)row * nChunks + c];
    float v = p.x; int id = __float_as_int(p.y);
    if (id >= 0) {
      if (v > v1) { v2 = v1; i2 = i1; v1 = v; i1 = id; }
      else if (v > v2) { v2 = v; i2 = id; }
    }
    v = p.z; id = __float_as_int(p.w);
    if (id >= 0) {
      if (v > v1) { v2 = v1; i2 = i1; v1 = v; i1 = id; }
      else if (v > v2) { v2 = v; i2 = id; }
    }
  }
  pairs[row] = make_int2(i1, i2);
}

// ============== sequential merge scan: column-sliced, no cross-thread deps ==============
// One block of 768 threads; thread t owns column t for every row -> each step's
// read-after-write hazards are within a single thread (compiler orders via waitcnt).
__global__ __launch_bounds__(768) void merge_scan(float* __restrict__ tok,
                                                  const int2* __restrict__ pairs,
                                                  int nm, float wa, float wb) {
  __shared__ int2 sp[4000];
  int t = threadIdx.x;
  for (int i = t; i < nm; i += 768) sp[i] = pairs[i];
  __syncthreads();
  for (int i = 0; i < nm; i++) {
    int a = sp[i].x, b = sp[i].y;
    float x = tok[(size_t)a * D + t];
    float y = tok[(size_t)b * D + t];
    float v = wa * x + wb * y;
    tok[(size_t)a * D + t] = v;
    tok[(size_t)b * D + t] = v;
  }
}

// ============== GEMM-NT: C(MxN) = A(MxK) @ B(NxK)^T + bias, optional exact GELU ==============
__global__ __launch_bounds__(256) void gemm_nt(const float* __restrict__ A,
                                               const float* __restrict__ B,
                                               const float* __restrict__ bias,
                                               float* __restrict__ C,
                                               int M, int N, int K, int act) {
  __shared__ float As[64][17];
  __shared__ float Bs[64][17];
  int tid = threadIdx.x;
  int rowBase = blockIdx.y * 64, colBase = blockIdx.x * 64;
  int tx = tid & 15, ty = tid >> 4;
  float acc[4][4] = {};
  int lr = tid >> 2, lk = (tid & 3) << 2;
  for (int kb = 0; kb < K; kb += 16) {
    int arow = rowBase + lr;
    float4 av = (arow < M) ? *(const float4*)&A[(size_t)arow * K + kb + lk]
                           : make_float4(0.f, 0.f, 0.f, 0.f);
    As[lr][lk + 0] = av.x; As[lr][lk + 1] = av.y; As[lr][lk + 2] = av.z; As[lr][lk + 3] = av.w;
    int brow = colBase + lr;
    float4 bv = (brow < N) ? *(const float4*)&B[(size_t)brow * K + kb + lk]
                           : make_float4(0.f, 0.f, 0.f, 0.f);
    Bs[lr][lk + 0] = bv.x; Bs[lr][lk + 1] = bv.y; Bs[lr][lk + 2] = bv.z; Bs[lr][lk + 3] = bv.w;
    __syncthreads();
#pragma unroll
    for (int kk = 0; kk < 16; kk++) {
      float a0 = As[ty * 4 + 0][kk], a1 = As[ty * 4 + 1][kk];
      float a2 = As[ty * 4 + 2][kk], a3 = As[ty * 4 + 3][kk];
      float b0 = Bs[tx * 4 + 0][kk], b1 = Bs[tx * 4 + 1][kk];
      float b2 = Bs[tx * 4 + 2][kk], b3 = Bs[tx * 4 + 3][kk];
      acc[0][0] += a0 * b0; acc[0][1] += a0 * b1; acc[0][2] += a0 * b2; acc[0][3] += a0 * b3;
      acc[1][0] += a1 * b0; acc[1][1] += a1 * b1; acc[1][2] += a1 * b2; acc[1][3] += a1 * b3;
      acc[2][0] += a2 * b0; acc[2][1] += a2 * b1; acc[2][2] += a2 * b2; acc[2][3] += a2 * b3;
      acc[3][0] += a3 * b0; acc[3][1] += a3 * b1; acc[3][2] += a3 * b2; acc[3][3] += a3 * b3;
    }
    __syncthreads();
  }
#pragma unroll
  for (int i = 0; i < 4; i++)
#pragma unroll
    for (int j = 0; j < 4; j++) {
      int row = rowBase + ty * 4 + i, col = colBase + tx * 4 + j;
      if (row < M && col < N) {
        float v = acc[i][j] + bias[col];
        if (act == 1) v = 0.5f * v * (1.0f + erff(v * 0.70710678118654752f));
        C[(size_t)row * N + col] = v;
      }
    }
}

// ============== fused flash-style MHA (fp32), 8 queries/block, 64-key chunks ==============
#define QT 8
__global__ __launch_bounds__(256) void attn_k(const float* __restrict__ qkv,
                                              float* __restrict__ attnb, int L) {
  int h = blockIdx.y;
  int q0 = blockIdx.x * QT;
  __shared__ float qs[QT][97];
  __shared__ float ks[64][97];
  __shared__ float vs[64][97];
  __shared__ float ss[QT][65];
  __shared__ float oacc[QT][96];
  __shared__ float mrow[QT], lrow[QT], corr[QT];
  int tid = threadIdx.x;
  const float scale = 0.10206207261596577f;  // 1/sqrt(96)
  for (int p = tid; p < QT * 96; p += 256) {
    int i = p / 96, d = p % 96;
    int qr = q0 + i;
    qs[i][d] = (qr < L) ? qkv[(size_t)qr * 2304 + h * 96 + d] : 0.f;
    oacc[i][d] = 0.f;
  }
  if (tid < QT) { mrow[tid] = -INFINITY; lrow[tid] = 0.f; }
  __syncthreads();
  for (int c0 = 0; c0 < L; c0 += 64) {
    int cn = min(64, L - c0);
    for (int p = tid; p < 64 * 96; p += 256) {
      int r = p / 96, d = p % 96;
      int kr = c0 + r;
      bool ok = r < cn;
      ks[r][d] = ok ? qkv[(size_t)kr * 2304 + 768 + h * 96 + d] : 0.f;
      vs[r][d] = ok ? qkv[(size_t)kr * 2304 + 1536 + h * 96 + d] : 0.f;
    }
    __syncthreads();
    {
      int i = tid >> 5;           // 0..7
      int j0 = (tid & 31) << 1;   // 0..62
      float a0 = 0.f, a1 = 0.f;
      for (int d = 0; d < 96; d++) {
        float q = qs[i][d];
        a0 += q * ks[j0][d];
        a1 += q * ks[j0 + 1][d];
      }
      ss[i][j0] = a0 * scale;
      ss[i][j0 + 1] = a1 * scale;
    }
    __syncthreads();
    if (tid < QT) {
      int i = tid;
      float m = mrow[i];
      float cm = -INFINITY;
      for (int j = 0; j < cn; j++) cm = fmaxf(cm, ss[i][j]);
      float nm = fmaxf(m, cm);
      float cr = expf(m - nm);  // m = -inf on first chunk -> 0
      float sum = 0.f;
      for (int j = 0; j < cn; j++) { float p = expf(ss[i][j] - nm); ss[i][j] = p; sum += p; }
      lrow[i] = lrow[i] * cr + sum;
      mrow[i] = nm;
      corr[i] = cr;
    }
    __syncthreads();
    for (int p = tid; p < QT * 96; p += 256) {
      int i = p / 96, d = p % 96;
      float a = oacc[i][d] * corr[i];
      for (int j = 0; j < cn; j++) a += ss[i][j] * vs[j][d];
      oacc[i][d] = a;
    }
    __syncthreads();
  }
  for (int p = tid; p < QT * 96; p += 256) {
    int i = p / 96, d = p % 96;
    int qr = q0 + i;
    if (qr < L) attnb[(size_t)qr * D + h * 96 + d] = oacc[i][d] / lrow[i];
  }
}

// ============== residual add + LayerNorm (one row per block) ==============
__global__ __launch_bounds__(256) void res_ln(const float* __restrict__ x,
                                              const float* __restrict__ r,
                                              const float* __restrict__ g,
                                              const float* __restrict__ b,
                                              float* __restrict__ out, int M) {
  int row = blockIdx.x;
  if (row >= M) return;
  __shared__ float buf[D];
  __shared__ float wred[4];
  __shared__ float stats[2];
  int tid = threadIdx.x;
  float s = 0.f;
  for (int k = tid; k < D; k += 256) {
    float v = x[(size_t)row * D + k] + r[(size_t)row * D + k];
    buf[k] = v;
    s += v;
  }
#pragma unroll
  for (int off = 32; off > 0; off >>= 1) s += __shfl_down(s, off);
  if ((tid & 63) == 0) wred[tid >> 6] = s;
  __syncthreads();
  if (tid == 0) stats[0] = (wred[0] + wred[1] + wred[2] + wred[3]) * (1.0f / D);
  __syncthreads();
  float mean = stats[0];
  float s2 = 0.f;
  for (int k = tid; k < D; k += 256) { float d0 = buf[k] - mean; s2 += d0 * d0; }
#pragma unroll
  for (int off = 32; off > 0; off >>= 1) s2 += __shfl_down(s2, off);
  __syncthreads();
  if ((tid & 63) == 0) wred[tid >> 6] = s2;
  __syncthreads();
  if (tid == 0)
    stats[1] = rsqrtf((wred[0] + wred[1] + wred[2] + wred[3]) * (1.0f / D) + 1e-5f);
  __syncthreads();
  float rstd = stats[1];
  for (int k = tid; k < D; k += 256)
    out[(size_t)row * D + k] = (buf[k] - mean) * rstd * g[k] + b[k];
}

// ============================ launcher ============================
extern "C" void kernel_launch(void* const* d_in, const int* in_sizes, int n_in,
                              void* d_out, int out_size, void* d_ws, size_t ws_size,
                              hipStream_t stream) {
  (void)in_sizes; (void)n_in; (void)out_size; (void)ws_size;
  const float* vf   = (const float*)d_in[0];   // 160*50*768
  const float* Wqkv = (const float*)d_in[1];   // 2304x768
  const float* bqkv = (const float*)d_in[2];
  const float* Wo   = (const float*)d_in[3];   // 768x768
  const float* bo   = (const float*)d_in[4];
  const float* ln1g = (const float*)d_in[5];
  const float* ln1b = (const float*)d_in[6];
  const float* W1   = (const float*)d_in[7];   // 3072x768
  const float* b1   = (const float*)d_in[8];
  const float* W2   = (const float*)d_in[9];   // 768x3072
  const float* b2   = (const float*)d_in[10];
  const float* ln2g = (const float*)d_in[11];
  const float* ln2b = (const float*)d_in[12];

  float* ws = (float*)d_ws;
  // workspace layout (floats); total extent = 14,304,000 floats = 57.2 MB
  float*  tok   = ws;                                // 8000*768
  float*  norms = ws + 6144000;                      // 8000
  float4* part  = (float4*)(ws + 6152000);           // up to 4000*125 float4
  int2*   pairs = (int2*)(ws + 8152000);             // up to 4000 int2
  float*  qkv   = ws + 8160000;                      // 2000*2304
  float*  attnb = ws + 12768000;                     // 2000*768
  float*  projb = ws + 8160000;                      // reuse (qkv dead)
  float*  hid   = ws + 8160000;                      // reuse (projb dead) 1500*3072
  float*  ffnb  = ws + 12768000;                     // reuse (attnb dead) 1500*768
  float*  outp  = (float*)d_out;

  // tokens <- input copy (inputs must not be mutated)
  copy_f4<<<6000, 256, 0, stream>>>((const float4*)vf, (float4*)tok, 1536000);

  // ---- merge 1: 8000 -> 4000, wa=wb=0.5 ----
  norms_k<<<8000, 64, 0, stream>>>(tok, norms, 8000);
  sim_top2_part<<<dim3(125, 125), 256, 0, stream>>>(tok, norms, 4000, 8000, 125, part);
  top2_reduce<<<(4000 + 255) / 256, 256, 0, stream>>>(part, 4000, 125, pairs);
  merge_scan<<<1, 768, 0, stream>>>(tok, pairs, 4000, 0.5f, 0.5f);

  // ---- merge 2: 4000 -> 2000, wa=wb=0.5 ----
  norms_k<<<4000, 64, 0, stream>>>(tok, norms, 4000);
  sim_top2_part<<<dim3(63, 63), 256, 0, stream>>>(tok, norms, 2000, 4000, 63, part);
  top2_reduce<<<(2000 + 255) / 256, 256, 0, stream>>>(part, 2000, 63, pairs);
  merge_scan<<<1, 768, 0, stream>>>(tok, pairs, 2000, 0.5f, 0.5f);

  // ---- MHA over 2000 tokens ----
  gemm_nt<<<dim3(2304 / 64, (2000 + 63) / 64), 256, 0, stream>>>(
      tok, Wqkv, bqkv, qkv, 2000, 2304, 768, 0);
  attn_k<<<dim3(2000 / QT, 8), 256, 0, stream>>>(qkv, attnb, 2000);
  gemm_nt<<<dim3(768 / 64, (2000 + 63) / 64), 256, 0, stream>>>(
      attnb, Wo, bo, projb, 2000, 768, 768, 0);
  res_ln<<<2000, 256, 0, stream>>>(tok, projb, ln1g, ln1b, tok, 2000);

  // ---- merge 3: 2000 -> 1500, wa=0.6, wb=0.4 ----
  norms_k<<<2000, 64, 0, stream>>>(tok, norms, 2000);
  sim_top2_part<<<dim3(32, 16), 256, 0, stream>>>(tok, norms, 500, 2000, 32, part);
  top2_reduce<<<(500 + 255) / 256, 256, 0, stream>>>(part, 500, 32, pairs);
  merge_scan<<<1, 768, 0, stream>>>(tok, pairs, 500, 0.6f, 0.4f);

  // ---- FFN over 1500 tokens + final LN -> d_out ----
  gemm_nt<<<dim3(3072 / 64, (1500 + 63) / 64), 256, 0, stream>>>(
      tok, W1, b1, hid, 1500, 3072, 768, 1);
  gemm_nt<<<dim3(768 / 64, (1500 + 63) / 64), 256, 0, stream>>>(
      hid, W2, b2, ffnb, 1500, 768, 3072, 0);
  res_ln<<<1500, 256, 0, stream>>>(tok, ffnb, ln2g, ln2b, outp, 1500);
}